// Round 11
// baseline (207.203 us; speedup 1.0000x reference)
//
#include <hip/hip_runtime.h>

#define GN   1024
#define GNN  (GN * GN)
#define GP   16
#define NOUT 127          // ys[1:] = T_1 .. T_127
#define TI   64           // output tile side
#define KH   16           // halo depth = max fused steps per launch
#define SZI  96           // region side (TI + 2*KH)
#define NRB  24           // row-blocks  (SZI/4)
#define NCB  24           // col-blocks  (SZI/4)
#define NTHR 576          // NRB*NCB threads, 9 waves
#define RST  100          // row-plane stride (floats), 4-aligned
#define AXB  (NRB * 2 * RST)            // aux base within plane = 4800
#define AXS  ((NCB + 1) * RST)          // one aux side = 2500
#define PLN  (AXB + 2 * AXS)            // plane floats = 9800 (39.2 KB)

// Exact fp32 constants: DT/dx^2 = 1e-7*1023^2 = 0.1046529, DT/(2dx) = 5.115e-5

__device__ __forceinline__ void coord16(int t, int& c0, int& c1, float& w) {
    // coords = linspace(0, 15, 1024): c = t * 15/1023
    double c = (double)t * (15.0 / 1023.0);
    c0 = (int)c;
    c1 = c0 + 1 > 15 ? 15 : c0 + 1;
    w  = (float)(c - (double)c0);
}

__device__ __forceinline__ float bilin16(const float* __restrict__ m,
                                         int i0, int i1, float wi,
                                         int j0, int j1, float wj) {
    float m00 = m[i0 * GP + j0];
    float m10 = m[i1 * GP + j0];
    float m01 = m[i0 * GP + j1];
    float m11 = m[i1 * GP + j1];
    float r0 = m00 * (1.0f - wi) + m10 * wi;
    float r1 = m01 * (1.0f - wi) + m11 * wi;
    return r0 * (1.0f - wj) + r1 * wj;
}

__device__ __forceinline__ float cellv(float C, float L, float R, float U, float D,
                                       float a2, float k2) {
    // val = C - k2*C*((D-U)+(R-L)) + a2*(U+D+L+R-4C)
    float s   = (D - U) + (R - L);
    float lap = fmaf(-4.0f, C, (U + D) + (L + R));
    return fmaf(a2, lap, fmaf(-k2, C * s, C));
}

// One 4-wide row of cells: verified column shift-select logic (rounds 4-7).
__device__ __forceinline__ float4 rowcell(float4 v, float4 U, float4 D,
                                          float sl, float sr,
                                          float4 a2, float4 k2,
                                          bool isl, bool isr) {
    float L0 = isl ? v.x : sl;
    float C0 = isl ? v.y : v.x;
    float R0 = isl ? v.z : v.y;
    float U0 = isl ? U.y : U.x;
    float D0 = isl ? D.y : D.x;
    float L3 = isr ? v.y : v.z;
    float C3 = isr ? v.z : v.w;
    float R3 = isr ? v.w : sr;
    float U3 = isr ? U.z : U.w;
    float D3 = isr ? D.z : D.w;
    float4 nv;
    nv.x = cellv(C0,  L0,  R0,  U0,  D0,  a2.x, k2.x);
    nv.y = cellv(v.y, v.x, v.z, U.y, D.y, a2.y, k2.y);
    nv.z = cellv(v.z, v.y, v.w, U.z, D.z, a2.z, k2.z);
    nv.w = cellv(C3,  L3,  R3,  U3,  D3,  a2.w, k2.w);
    return nv;
}

// Barrier that waits LDS ops ONLY — no "memory" clobber, so the waitcnt pass
// does NOT insert s_waitcnt vmcnt(0) (the m97 barrier-drain stall; with the
// clobber present, rounds 5-10 still drained all global stores every step).
// Ordering is enforced by (a) sched_barrier(0) fences on both sides (blocks
// scheduler movement of the preceding ds_writes across it, rule #18) and
// (b) the returned opaque zero being folded into the plane pointers each
// iteration, making every subsequent DS address DATA-DEPEND on the barrier
// (no hoist, no cross-iteration CSE of LDS reads).
__device__ __forceinline__ int lds_barrier_dep() {
    int z;
    __builtin_amdgcn_sched_barrier(0);
    asm volatile("s_waitcnt lgkmcnt(0)\n\t"
                 "s_barrier\n\t"
                 "s_mov_b32 %0, 0" : "=s"(z));
    __builtin_amdgcn_sched_barrier(0);
    return z;
}

// Clamp-baked, pre-scaled coefficient maps.
__global__ __launch_bounds__(256)
void resize_maps_kernel(const float* __restrict__ alpha,
                        const float* __restrict__ kappa,
                        float* __restrict__ a2map,
                        float* __restrict__ k2map) {
    int idx = blockIdx.x * 256 + threadIdx.x;
    if (idx >= GNN) return;
    int i = idx >> 10;
    int j = idx & (GN - 1);
    int ci = i < 1 ? 1 : (i > GN - 2 ? GN - 2 : i);
    int cj = j < 1 ? 1 : (j > GN - 2 ? GN - 2 : j);
    int i0, i1, j0, j1; float wi, wj;
    coord16(ci, i0, i1, wi);
    coord16(cj, j0, j1, wj);
    a2map[idx] = bilin16(alpha, i0, i1, wi, j0, j1, wj) * 0.1046529f;
    k2map[idx] = bilin16(kappa, i0, i1, wi, j0, j1, wj) * 5.115e-5f;
}

// Temporal-blocked stepper, stale-halo scheme (verified rounds 4-7), with
// row-window staleness skip (round 10) and the non-draining barrier above.
template <bool USE_WS>
__global__ __launch_bounds__(NTHR)
void fused_steps_kernel(const float* __restrict__ srcp,
                        const float* __restrict__ Aarg,   // a2map or alpha
                        const float* __restrict__ Karg,   // k2map or kappa
                        float* __restrict__ out,
                        int base)
{
    __shared__ float lds[2][PLN];   // 2 x 39.2 KB

    const int tid = threadIdx.x;
    const int rb  = tid / NCB;
    const int cb  = tid - rb * NCB;
    const int r0  = rb * 4;
    const int c4  = cb * 4;

    const int gi0 = blockIdx.y * TI;
    const int gj0 = blockIdx.x * TI;
    int oi = gi0 - KH; oi = oi < 0 ? 0 : (oi > GN - SZI ? GN - SZI : oi);
    int oj = gj0 - KH; oj = oj < 0 ? 0 : (oj > GN - SZI ? GN - SZI : oj);
    const int di = gi0 - oi;           // 0, 16, or 32
    const int dj = gj0 - oj;

    const bool istop = (rb == 0), isbot = (rb == NRB - 1);
    const bool isl   = (cb == 0), isr   = (cb == NCB - 1);
    const bool core  = (rb >= (di >> 2)) && (rb < (di >> 2) + TI / 4)
                    && (cb >= (dj >> 2)) && (cb < (dj >> 2) + TI / 4);
    const int  tmax  = NOUT - base;
    const int  kk    = tmax < KH ? tmax : KH;   // steps this launch

    const long gbase = (long)(oi + r0) * GN + oj + c4;

    const int uoff   = (istop ? 0 : (rb * 2 - 1)) * RST + c4;
    const int doff   = (isbot ? (NRB * 2 - 1) : (rb * 2 + 2)) * RST + c4;
    const int w0off  = (rb * 2) * RST + c4;
    const int w3off  = (rb * 2 + 1) * RST + c4;
    const int sloff  = AXB + cb * RST + rb * 4;
    const int wsloff = AXB + (cb + 1) * RST + rb * 4;
    const int sroff  = AXB + AXS + (cb + 1) * RST + rb * 4;
    const int wsroff = AXB + AXS + cb * RST + rb * 4;

    float4 a2[4], k2[4];
    if (USE_WS) {
        #pragma unroll
        for (int q = 0; q < 4; ++q) {
            a2[q] = *(const float4*)(Aarg + gbase + q * GN);
            k2[q] = *(const float4*)(Karg + gbase + q * GN);
        }
    } else {
        #pragma unroll
        for (int q = 0; q < 4; ++q) {
            int gi = oi + r0 + q;
            int ci = gi < 1 ? 1 : (gi > GN - 2 ? GN - 2 : gi);
            int i0, i1; float wi;
            coord16(ci, i0, i1, wi);
            float av[4], kv[4];
            #pragma unroll
            for (int u = 0; u < 4; ++u) {
                int gj = oj + c4 + u;
                int cj = gj < 1 ? 1 : (gj > GN - 2 ? GN - 2 : gj);
                int j0, j1; float wj;
                coord16(cj, j0, j1, wj);
                av[u] = bilin16(Aarg, i0, i1, wi, j0, j1, wj) * 0.1046529f;
                kv[u] = bilin16(Karg, i0, i1, wi, j0, j1, wj) * 5.115e-5f;
            }
            a2[q] = make_float4(av[0], av[1], av[2], av[3]);
            k2[q] = make_float4(kv[0], kv[1], kv[2], kv[3]);
        }
    }

    // Seed: raw rows to LDS plane 0; CLAMPED rows to register carry.
    float4 V[4];
    {
        float4 ld0 = *(const float4*)(srcp + gbase);
        float4 ld1 = *(const float4*)(srcp + gbase + GN);
        float4 ld2 = *(const float4*)(srcp + gbase + 2 * GN);
        float4 ld3 = *(const float4*)(srcp + gbase + 3 * GN);
        *(float4*)&lds[0][w0off]  = ld0;
        *(float4*)&lds[0][w3off]  = ld3;
        *(float4*)&lds[0][wsloff] = make_float4(ld0.w, ld1.w, ld2.w, ld3.w);
        *(float4*)&lds[0][wsroff] = make_float4(ld0.x, ld1.x, ld2.x, ld3.x);
        V[0] = istop ? ld1 : ld0;
        V[1] = ld1;
        V[2] = ld2;
        V[3] = isbot ? ld2 : ld3;
    }
    __syncthreads();   // once per launch (also drains seed loads)

    const float* cur = &lds[0][0];
    float*       nxt = &lds[1][0];
    const int ahi_s = di + TI - 1;     // core row range [di, ahi_s]

    #pragma unroll 1
    for (int t = 1; t <= kk; ++t) {
        const int marg = KH - t;
        int alo = di - marg;      if (alo < 0) alo = 0;
        int ahi = ahi_s + marg;   if (ahi > SZI - 1) ahi = SZI - 1;

        if (r0 + 3 >= alo && r0 <= ahi) {
            float4 U  = *(const float4*)(cur + uoff);
            float4 D  = *(const float4*)(cur + doff);
            float4 SL = *(const float4*)(cur + sloff);
            float4 SR = *(const float4*)(cur + sroff);

            float4 Uop1 = istop ? U : V[0];
            float4 Dop2 = isbot ? D : V[3];

            float4 NV0 = rowcell(V[0], U,    V[1], SL.x, SR.x, a2[0], k2[0], isl, isr);
            float4 NV1 = rowcell(V[1], Uop1, V[2], SL.y, SR.y, a2[1], k2[1], isl, isr);
            float4 NV2 = rowcell(V[2], V[1], Dop2, SL.z, SR.z, a2[2], k2[2], isl, isr);
            float4 NV3 = rowcell(V[3], V[2], D,    SL.w, SR.w, a2[3], k2[3], isl, isr);
            if (istop) NV0 = NV1;             // replica rows
            if (isbot) NV3 = NV2;

            *(float4*)(nxt + w0off)  = NV0;
            *(float4*)(nxt + w3off)  = NV3;
            *(float4*)(nxt + wsloff) = make_float4(NV0.w, NV1.w, NV2.w, NV3.w);
            *(float4*)(nxt + wsroff) = make_float4(NV0.x, NV1.x, NV2.x, NV3.x);

            if (core) {
                float* slab = out + (long)(base + t - 1) * GNN;
                *(float4*)(slab + gbase)          = NV0;
                *(float4*)(slab + gbase + GN)     = NV1;
                *(float4*)(slab + gbase + 2 * GN) = NV2;
                *(float4*)(slab + gbase + 3 * GN) = NV3;
            }
            V[0] = NV0; V[1] = NV1; V[2] = NV2; V[3] = NV3;
        }

        // Non-draining barrier; fold its opaque zero into BOTH plane pointers
        // so every next-step DS address data-depends on the barrier.
        int z = lds_barrier_dep();
        float* t2 = (float*)cur + z;
        cur = nxt + z;
        nxt = t2;
    }
}

extern "C" void kernel_launch(void* const* d_in, const int* in_sizes, int n_in,
                              void* d_out, int out_size, void* d_ws, size_t ws_size,
                              hipStream_t stream) {
    const float* u0    = (const float*)d_in[0];
    const float* alpha = (const float*)d_in[1];
    const float* kappa = (const float*)d_in[2];
    float* out = (float*)d_out;

    dim3 grd(GN / TI, GN / TI, 1);   // 16x16 = 256 blocks = 1/CU
    dim3 blk(NTHR, 1, 1);

    bool use_ws = ws_size >= (size_t)2 * GNN * sizeof(float);

    if (use_ws) {
        float* a2map = (float*)d_ws;
        float* k2map = a2map + GNN;
        resize_maps_kernel<<<(GNN + 255) / 256, 256, 0, stream>>>(alpha, kappa, a2map, k2map);
        for (int b = 0; b < NOUT; b += KH) {
            const float* src = (b == 0) ? u0 : out + (long)(b - 1) * GNN;
            fused_steps_kernel<true><<<grd, blk, 0, stream>>>(src, a2map, k2map, out, b);
        }
    } else {
        for (int b = 0; b < NOUT; b += KH) {
            const float* src = (b == 0) ? u0 : out + (long)(b - 1) * GNN;
            fused_steps_kernel<false><<<grd, blk, 0, stream>>>(src, alpha, kappa, out, b);
        }
    }
}

// Round 12
// 201.076 us; speedup vs baseline: 1.0305x; 1.0305x over previous
//
#include <hip/hip_runtime.h>

#define GN   1024
#define GNN  (GN * GN)
#define GP   16
#define NOUT 127          // ys[1:] = T_1 .. T_127
#define TI   64           // output tile side
#define KH   16           // halo depth = fused steps per launch
#define SZI  96           // region side (TI + 2*KH)
#define NRB  24           // row-blocks  (SZI/4)
#define NCB  24           // col-blocks  (SZI/4)
#define NTHR 576          // NRB*NCB threads, 9 waves
#define RST  100          // row-plane stride (floats), 4-aligned
#define AXB  (NRB * 2 * RST)            // aux base within plane = 4800
#define AXS  ((NCB + 1) * RST)          // one aux side = 2500
#define PLN  (AXB + 2 * AXS)            // plane floats = 9800 (39.2 KB)

// Exact fp32 constants: DT/dx^2 = 1e-7*1023^2 = 0.1046529, DT/(2dx) = 5.115e-5

__device__ __forceinline__ void coord16(int t, int& c0, int& c1, float& w) {
    // coords = linspace(0, 15, 1024): c = t * 15/1023
    double c = (double)t * (15.0 / 1023.0);
    c0 = (int)c;
    c1 = c0 + 1 > 15 ? 15 : c0 + 1;
    w  = (float)(c - (double)c0);
}

__device__ __forceinline__ float bilin16(const float* __restrict__ m,
                                         int i0, int i1, float wi,
                                         int j0, int j1, float wj) {
    float m00 = m[i0 * GP + j0];
    float m10 = m[i1 * GP + j0];
    float m01 = m[i0 * GP + j1];
    float m11 = m[i1 * GP + j1];
    float r0 = m00 * (1.0f - wi) + m10 * wi;
    float r1 = m01 * (1.0f - wi) + m11 * wi;
    return r0 * (1.0f - wj) + r1 * wj;
}

__device__ __forceinline__ float cellv(float C, float L, float R, float U, float D,
                                       float a2, float k2) {
    // val = C - k2*C*((D-U)+(R-L)) + a2*(U+D+L+R-4C)
    float s   = (D - U) + (R - L);
    float lap = fmaf(-4.0f, C, (U + D) + (L + R));
    return fmaf(a2, lap, fmaf(-k2, C * s, C));
}

// Plain (unshifted) 4-wide row stencil — NO edge selects. Edge strips consume
// garbage sl/sr and their edge cell is then REPLACED by a replica copy, which
// is bitwise identical to the old shifted-stencil result (clamped coeffs ==
// neighbor coeffs, clamped operands == neighbor operands).
__device__ __forceinline__ float4 rowcell(float4 v, float4 U, float4 D,
                                          float sl, float sr,
                                          float4 a2, float4 k2) {
    float4 nv;
    nv.x = cellv(v.x, sl,  v.y, U.x, D.x, a2.x, k2.x);
    nv.y = cellv(v.y, v.x, v.z, U.y, D.y, a2.y, k2.y);
    nv.z = cellv(v.z, v.y, v.w, U.z, D.z, a2.z, k2.z);
    nv.w = cellv(v.w, v.z, sr,  U.w, D.w, a2.w, k2.w);
    return nv;
}

// LDS barrier (memory clobber; r11 proved vmcnt-drain is perf-neutral here,
// so keep the provably-safe form; rule #18 fencing).
__device__ __forceinline__ void lds_barrier() {
    __builtin_amdgcn_sched_barrier(0);
    asm volatile("s_waitcnt lgkmcnt(0)" ::: "memory");
    __builtin_amdgcn_s_barrier();
    __builtin_amdgcn_sched_barrier(0);
}

// Clamp-baked, pre-scaled coefficient maps.
__global__ __launch_bounds__(256)
void resize_maps_kernel(const float* __restrict__ alpha,
                        const float* __restrict__ kappa,
                        float* __restrict__ a2map,
                        float* __restrict__ k2map) {
    int idx = blockIdx.x * 256 + threadIdx.x;
    if (idx >= GNN) return;
    int i = idx >> 10;
    int j = idx & (GN - 1);
    int ci = i < 1 ? 1 : (i > GN - 2 ? GN - 2 : i);
    int cj = j < 1 ? 1 : (j > GN - 2 ? GN - 2 : j);
    int i0, i1, j0, j1; float wi, wj;
    coord16(ci, i0, i1, wi);
    coord16(cj, j0, j1, wj);
    a2map[idx] = bilin16(alpha, i0, i1, wi, j0, j1, wj) * 0.1046529f;
    k2map[idx] = bilin16(kappa, i0, i1, wi, j0, j1, wj) * 5.115e-5f;
}

// Temporal-blocked stepper, stale-halo scheme (rounds 4-11), restructured:
//  - replica-copy edge handling (no shifted-stencil selects): compute plain
//    stencil everywhere, then NV0=NV1 / NV3=NV2 / NV.x=NV.y / NV.w=NV.z on
//    the replica strips. Row 1/2's U/D operands come UNCONDITIONALLY from the
//    register carry (V[0]/V[3] hold raw values at t=1 and replica values
//    after — both correct).
//  - all-raw seeding (clamped-seed loads no longer needed).
//  - FULL 16-step unroll with compile-time plane parity: LDS addresses are
//    loop-invariant and hoist into registers; no pointer-swap dep chain.
template <bool USE_WS>
__global__ __launch_bounds__(NTHR)
void fused_steps_kernel(const float* __restrict__ srcp,
                        const float* __restrict__ Aarg,   // a2map or alpha
                        const float* __restrict__ Karg,   // k2map or kappa
                        float* __restrict__ out,
                        int base)
{
    __shared__ float lds[2][PLN];   // 2 x 39.2 KB

    const int tid = threadIdx.x;
    const int rb  = tid / NCB;
    const int cb  = tid - rb * NCB;
    const int r0  = rb * 4;
    const int c4  = cb * 4;

    const int gi0 = blockIdx.y * TI;
    const int gj0 = blockIdx.x * TI;
    int oi = gi0 - KH; oi = oi < 0 ? 0 : (oi > GN - SZI ? GN - SZI : oi);
    int oj = gj0 - KH; oj = oj < 0 ? 0 : (oj > GN - SZI ? GN - SZI : oj);
    const int di = gi0 - oi;           // 0, 16, or 32
    const int dj = gj0 - oj;

    const bool istop = (rb == 0), isbot = (rb == NRB - 1);
    const bool isl   = (cb == 0), isr   = (cb == NCB - 1);
    const bool core  = (rb >= (di >> 2)) && (rb < (di >> 2) + TI / 4)
                    && (cb >= (dj >> 2)) && (cb < (dj >> 2) + TI / 4);
    const int  tmax  = NOUT - base;    // stores only for t <= tmax

    const long gbase = (long)(oi + r0) * GN + oj + c4;

    const int uoff   = (istop ? 0 : (rb * 2 - 1)) * RST + c4;
    const int doff   = (isbot ? (NRB * 2 - 1) : (rb * 2 + 2)) * RST + c4;
    const int w0off  = (rb * 2) * RST + c4;
    const int w3off  = (rb * 2 + 1) * RST + c4;
    const int sloff  = AXB + cb * RST + rb * 4;
    const int wsloff = AXB + (cb + 1) * RST + rb * 4;
    const int sroff  = AXB + AXS + (cb + 1) * RST + rb * 4;
    const int wsroff = AXB + AXS + cb * RST + rb * 4;

    float4 a2[4], k2[4];
    if (USE_WS) {
        #pragma unroll
        for (int q = 0; q < 4; ++q) {
            a2[q] = *(const float4*)(Aarg + gbase + q * GN);
            k2[q] = *(const float4*)(Karg + gbase + q * GN);
        }
    } else {
        #pragma unroll
        for (int q = 0; q < 4; ++q) {
            int gi = oi + r0 + q;
            int ci = gi < 1 ? 1 : (gi > GN - 2 ? GN - 2 : gi);
            int i0, i1; float wi;
            coord16(ci, i0, i1, wi);
            float av[4], kv[4];
            #pragma unroll
            for (int u = 0; u < 4; ++u) {
                int gj = oj + c4 + u;
                int cj = gj < 1 ? 1 : (gj > GN - 2 ? GN - 2 : gj);
                int j0, j1; float wj;
                coord16(cj, j0, j1, wj);
                av[u] = bilin16(Aarg, i0, i1, wi, j0, j1, wj) * 0.1046529f;
                kv[u] = bilin16(Karg, i0, i1, wi, j0, j1, wj) * 5.115e-5f;
            }
            a2[q] = make_float4(av[0], av[1], av[2], av[3]);
            k2[q] = make_float4(kv[0], kv[1], kv[2], kv[3]);
        }
    }

    // All-raw seed: LDS boundary rows + aux columns + register carry.
    float4 V[4];
    {
        float4 ld0 = *(const float4*)(srcp + gbase);
        float4 ld1 = *(const float4*)(srcp + gbase + GN);
        float4 ld2 = *(const float4*)(srcp + gbase + 2 * GN);
        float4 ld3 = *(const float4*)(srcp + gbase + 3 * GN);
        *(float4*)&lds[0][w0off]  = ld0;
        *(float4*)&lds[0][w3off]  = ld3;
        *(float4*)&lds[0][wsloff] = make_float4(ld0.w, ld1.w, ld2.w, ld3.w);
        *(float4*)&lds[0][wsroff] = make_float4(ld0.x, ld1.x, ld2.x, ld3.x);
        V[0] = ld0; V[1] = ld1; V[2] = ld2; V[3] = ld3;
    }
    __syncthreads();

    const int ahi_s = di + TI - 1;     // core row range [di, ahi_s]

    #pragma unroll
    for (int t = 1; t <= KH; ++t) {
        const float* cur = (t & 1) ? &lds[0][0] : &lds[1][0];
        float*       nxt = (t & 1) ? &lds[1][0] : &lds[0][0];

        const int marg = KH - t;                     // compile-time
        int alo = di - marg;      if (alo < 0) alo = 0;
        int ahi = ahi_s + marg;   if (ahi > SZI - 1) ahi = SZI - 1;

        if (r0 + 3 >= alo && r0 <= ahi) {
            float4 U  = *(const float4*)(cur + uoff);
            float4 D  = *(const float4*)(cur + doff);
            float4 SL = *(const float4*)(cur + sloff);
            float4 SR = *(const float4*)(cur + sroff);

            float4 NV0 = rowcell(V[0], U,    V[1], SL.x, SR.x, a2[0], k2[0]);
            float4 NV1 = rowcell(V[1], V[0], V[2], SL.y, SR.y, a2[1], k2[1]);
            float4 NV2 = rowcell(V[2], V[1], V[3], SL.z, SR.z, a2[2], k2[2]);
            float4 NV3 = rowcell(V[3], V[2], D,    SL.w, SR.w, a2[3], k2[3]);

            if (istop) NV0 = NV1;                    // row replicas first
            if (isbot) NV3 = NV2;
            if (isl) { NV0.x = NV0.y; NV1.x = NV1.y; // then column replicas
                       NV2.x = NV2.y; NV3.x = NV3.y; }
            if (isr) { NV0.w = NV0.z; NV1.w = NV1.z;
                       NV2.w = NV2.z; NV3.w = NV3.z; }

            *(float4*)(nxt + w0off)  = NV0;
            *(float4*)(nxt + w3off)  = NV3;
            *(float4*)(nxt + wsloff) = make_float4(NV0.w, NV1.w, NV2.w, NV3.w);
            *(float4*)(nxt + wsroff) = make_float4(NV0.x, NV1.x, NV2.x, NV3.x);

            if (core && t <= tmax) {
                float* slab = out + (long)(base + t - 1) * GNN;
                *(float4*)(slab + gbase)          = NV0;
                *(float4*)(slab + gbase + GN)     = NV1;
                *(float4*)(slab + gbase + 2 * GN) = NV2;
                *(float4*)(slab + gbase + 3 * GN) = NV3;
            }
            V[0] = NV0; V[1] = NV1; V[2] = NV2; V[3] = NV3;
        }
        lds_barrier();   // LDS-only wait; global stores drain in background
    }
}

extern "C" void kernel_launch(void* const* d_in, const int* in_sizes, int n_in,
                              void* d_out, int out_size, void* d_ws, size_t ws_size,
                              hipStream_t stream) {
    const float* u0    = (const float*)d_in[0];
    const float* alpha = (const float*)d_in[1];
    const float* kappa = (const float*)d_in[2];
    float* out = (float*)d_out;

    dim3 grd(GN / TI, GN / TI, 1);   // 16x16 = 256 blocks = 1/CU
    dim3 blk(NTHR, 1, 1);

    bool use_ws = ws_size >= (size_t)2 * GNN * sizeof(float);

    if (use_ws) {
        float* a2map = (float*)d_ws;
        float* k2map = a2map + GNN;
        resize_maps_kernel<<<(GNN + 255) / 256, 256, 0, stream>>>(alpha, kappa, a2map, k2map);
        for (int b = 0; b < NOUT; b += KH) {
            const float* src = (b == 0) ? u0 : out + (long)(b - 1) * GNN;
            fused_steps_kernel<true><<<grd, blk, 0, stream>>>(src, a2map, k2map, out, b);
        }
    } else {
        for (int b = 0; b < NOUT; b += KH) {
            const float* src = (b == 0) ? u0 : out + (long)(b - 1) * GNN;
            fused_steps_kernel<false><<<grd, blk, 0, stream>>>(src, alpha, kappa, out, b);
        }
    }
}

// Round 13
// 186.805 us; speedup vs baseline: 1.1092x; 1.0764x over previous
//
#include <hip/hip_runtime.h>

#define GN   1024
#define GNN  (GN * GN)
#define GP   16
#define NOUT 127          // ys[1:] = T_1 .. T_127
#define TI   64           // output tile side
#define KH   16           // halo depth = fused steps per launch
#define SZI  96           // region side (TI + 2*KH)
#define NRB  24           // row-blocks  (SZI/4)
#define NCB  24           // col-blocks  (SZI/4)
#define NTHR 576          // NRB*NCB threads, 9 waves
#define RST  100          // row-plane stride (floats), 4-aligned
#define AXB  (NRB * 2 * RST)            // aux base within plane = 4800
#define AXS  ((NCB + 1) * RST)          // one aux side = 2500
#define PLN  (AXB + 2 * AXS)            // plane floats = 9800 (39.2 KB)

typedef float f2 __attribute__((ext_vector_type(2)));

// ---- VOP3P packed-f32 primitives (dual IEEE fp32 per instruction; the
// compiler never auto-emits these for scalar HIP code). Pure ops, no
// side effects -> non-volatile asm, scheduler stays free.
__device__ __forceinline__ f2 pk_add(f2 a, f2 b) {
    f2 d; asm("v_pk_add_f32 %0, %1, %2" : "=v"(d) : "v"(a), "v"(b)); return d;
}
__device__ __forceinline__ f2 pk_sub(f2 a, f2 b) {   // a - b
    f2 d; asm("v_pk_add_f32 %0, %1, %2 neg_lo:[0,1] neg_hi:[0,1]"
              : "=v"(d) : "v"(a), "v"(b)); return d;
}
__device__ __forceinline__ f2 pk_mul(f2 a, f2 b) {
    f2 d; asm("v_pk_mul_f32 %0, %1, %2" : "=v"(d) : "v"(a), "v"(b)); return d;
}
__device__ __forceinline__ f2 pk_fma(f2 a, f2 b, f2 c) {   // a*b + c
    f2 d; asm("v_pk_fma_f32 %0, %1, %2, %3"
              : "=v"(d) : "v"(a), "v"(b), "v"(c)); return d;
}

// Exact fp32 constants: DT/dx^2 = 1e-7*1023^2 = 0.1046529, DT/(2dx) = 5.115e-5

__device__ __forceinline__ void coord16(int t, int& c0, int& c1, float& w) {
    double c = (double)t * (15.0 / 1023.0);
    c0 = (int)c;
    c1 = c0 + 1 > 15 ? 15 : c0 + 1;
    w  = (float)(c - (double)c0);
}

__device__ __forceinline__ float bilin16(const float* __restrict__ m,
                                         int i0, int i1, float wi,
                                         int j0, int j1, float wj) {
    float m00 = m[i0 * GP + j0];
    float m10 = m[i1 * GP + j0];
    float m01 = m[i0 * GP + j1];
    float m11 = m[i1 * GP + j1];
    float r0 = m00 * (1.0f - wi) + m10 * wi;
    float r1 = m01 * (1.0f - wi) + m11 * wi;
    return r0 * (1.0f - wj) + r1 * wj;
}

// Packed pair stencil — bitwise identical to the scalar cellv:
//   s = (D-U)+(R-L); lap = fma(-4,C,(U+D)+(L+R));
//   val = fma(a2, lap, fma(-k2, C*s, C))   (k2 pre-negated at setup)
__device__ __forceinline__ f2 pairv(f2 C, f2 L, f2 R, f2 U, f2 D,
                                    f2 a2, f2 nk2, f2 m4) {
    f2 s   = pk_add(pk_sub(D, U), pk_sub(R, L));
    f2 lap = pk_fma(m4, C, pk_add(pk_add(U, D), pk_add(L, R)));
    f2 cs  = pk_mul(C, s);
    return pk_fma(a2, lap, pk_fma(nk2, cs, C));
}

// LDS barrier (memory clobber; r11 proved vmcnt-drain is perf-neutral here).
__device__ __forceinline__ void lds_barrier() {
    __builtin_amdgcn_sched_barrier(0);
    asm volatile("s_waitcnt lgkmcnt(0)" ::: "memory");
    __builtin_amdgcn_s_barrier();
    __builtin_amdgcn_sched_barrier(0);
}

// Clamp-baked, pre-scaled coefficient maps.
__global__ __launch_bounds__(256)
void resize_maps_kernel(const float* __restrict__ alpha,
                        const float* __restrict__ kappa,
                        float* __restrict__ a2map,
                        float* __restrict__ k2map) {
    int idx = blockIdx.x * 256 + threadIdx.x;
    if (idx >= GNN) return;
    int i = idx >> 10;
    int j = idx & (GN - 1);
    int ci = i < 1 ? 1 : (i > GN - 2 ? GN - 2 : i);
    int cj = j < 1 ? 1 : (j > GN - 2 ? GN - 2 : j);
    int i0, i1, j0, j1; float wi, wj;
    coord16(ci, i0, i1, wi);
    coord16(cj, j0, j1, wj);
    a2map[idx] = bilin16(alpha, i0, i1, wi, j0, j1, wj) * 0.1046529f;
    k2map[idx] = bilin16(kappa, i0, i1, wi, j0, j1, wj) * 5.115e-5f;
}

// Temporal-blocked stepper (verified structure rounds 4-12) with the stencil
// re-expressed in packed-f32 pairs: row of 4 cells = pairs A=(c0,c1),
// B=(c2,c3); vertical operands pair for free; horizontal shifted pairs
// LA=(sl,c0), M=(c1,c2), RB=(c3,sr) are built with movs. Replica-copy edge
// handling, all-raw seed, full 16-step unroll, row-window skip unchanged.
template <bool USE_WS>
__global__ __launch_bounds__(NTHR)
void fused_steps_kernel(const float* __restrict__ srcp,
                        const float* __restrict__ Aarg,   // a2map or alpha
                        const float* __restrict__ Karg,   // k2map or kappa
                        float* __restrict__ out,
                        int base)
{
    __shared__ float lds[2][PLN];   // 2 x 39.2 KB

    const int tid = threadIdx.x;
    const int rb  = tid / NCB;
    const int cb  = tid - rb * NCB;
    const int r0  = rb * 4;
    const int c4  = cb * 4;

    const int gi0 = blockIdx.y * TI;
    const int gj0 = blockIdx.x * TI;
    int oi = gi0 - KH; oi = oi < 0 ? 0 : (oi > GN - SZI ? GN - SZI : oi);
    int oj = gj0 - KH; oj = oj < 0 ? 0 : (oj > GN - SZI ? GN - SZI : oj);
    const int di = gi0 - oi;           // 0, 16, or 32
    const int dj = gj0 - oj;

    const bool istop = (rb == 0), isbot = (rb == NRB - 1);
    const bool isl   = (cb == 0), isr   = (cb == NCB - 1);
    const bool core  = (rb >= (di >> 2)) && (rb < (di >> 2) + TI / 4)
                    && (cb >= (dj >> 2)) && (cb < (dj >> 2) + TI / 4);
    const int  tmax  = NOUT - base;    // stores only for t <= tmax

    const long gbase = (long)(oi + r0) * GN + oj + c4;

    const int uoff   = (istop ? 0 : (rb * 2 - 1)) * RST + c4;
    const int doff   = (isbot ? (NRB * 2 - 1) : (rb * 2 + 2)) * RST + c4;
    const int w0off  = (rb * 2) * RST + c4;
    const int w3off  = (rb * 2 + 1) * RST + c4;
    const int sloff  = AXB + cb * RST + rb * 4;
    const int wsloff = AXB + (cb + 1) * RST + rb * 4;
    const int sroff  = AXB + AXS + (cb + 1) * RST + rb * 4;
    const int wsroff = AXB + AXS + cb * RST + rb * 4;

    const f2 m4 = {-4.0f, -4.0f};

    // Coefficients as pairs; k2 PRE-NEGATED (exact sign flip).
    f2 a2A[4], a2B[4], nk2A[4], nk2B[4];
    if (USE_WS) {
        #pragma unroll
        for (int q = 0; q < 4; ++q) {
            float4 a = *(const float4*)(Aarg + gbase + q * GN);
            float4 k = *(const float4*)(Karg + gbase + q * GN);
            a2A[q]  = (f2){ a.x,  a.y };
            a2B[q]  = (f2){ a.z,  a.w };
            nk2A[q] = (f2){ -k.x, -k.y };
            nk2B[q] = (f2){ -k.z, -k.w };
        }
    } else {
        #pragma unroll
        for (int q = 0; q < 4; ++q) {
            int gi = oi + r0 + q;
            int ci = gi < 1 ? 1 : (gi > GN - 2 ? GN - 2 : gi);
            int i0, i1; float wi;
            coord16(ci, i0, i1, wi);
            float av[4], kv[4];
            #pragma unroll
            for (int u = 0; u < 4; ++u) {
                int gj = oj + c4 + u;
                int cj = gj < 1 ? 1 : (gj > GN - 2 ? GN - 2 : gj);
                int j0, j1; float wj;
                coord16(cj, j0, j1, wj);
                av[u] = bilin16(Aarg, i0, i1, wi, j0, j1, wj) * 0.1046529f;
                kv[u] = bilin16(Karg, i0, i1, wi, j0, j1, wj) * 5.115e-5f;
            }
            a2A[q]  = (f2){ av[0],  av[1] };
            a2B[q]  = (f2){ av[2],  av[3] };
            nk2A[q] = (f2){ -kv[0], -kv[1] };
            nk2B[q] = (f2){ -kv[2], -kv[3] };
        }
    }

    // All-raw seed: LDS boundary rows + aux columns + register carry (pairs).
    f2 vA0, vB0, vA1, vB1, vA2, vB2, vA3, vB3;
    {
        float4 ld0 = *(const float4*)(srcp + gbase);
        float4 ld1 = *(const float4*)(srcp + gbase + GN);
        float4 ld2 = *(const float4*)(srcp + gbase + 2 * GN);
        float4 ld3 = *(const float4*)(srcp + gbase + 3 * GN);
        *(float4*)&lds[0][w0off]  = ld0;
        *(float4*)&lds[0][w3off]  = ld3;
        *(float4*)&lds[0][wsloff] = make_float4(ld0.w, ld1.w, ld2.w, ld3.w);
        *(float4*)&lds[0][wsroff] = make_float4(ld0.x, ld1.x, ld2.x, ld3.x);
        vA0 = (f2){ld0.x, ld0.y}; vB0 = (f2){ld0.z, ld0.w};
        vA1 = (f2){ld1.x, ld1.y}; vB1 = (f2){ld1.z, ld1.w};
        vA2 = (f2){ld2.x, ld2.y}; vB2 = (f2){ld2.z, ld2.w};
        vA3 = (f2){ld3.x, ld3.y}; vB3 = (f2){ld3.z, ld3.w};
    }
    __syncthreads();

    const int ahi_s = di + TI - 1;     // core row range [di, ahi_s]

    #pragma unroll
    for (int t = 1; t <= KH; ++t) {
        const float* cur = (t & 1) ? &lds[0][0] : &lds[1][0];
        float*       nxt = (t & 1) ? &lds[1][0] : &lds[0][0];

        const int marg = KH - t;                     // compile-time
        int alo = di - marg;      if (alo < 0) alo = 0;
        int ahi = ahi_s + marg;   if (ahi > SZI - 1) ahi = SZI - 1;

        if (r0 + 3 >= alo && r0 <= ahi) {
            float4 U  = *(const float4*)(cur + uoff);
            float4 D  = *(const float4*)(cur + doff);
            float4 SL = *(const float4*)(cur + sloff);
            float4 SR = *(const float4*)(cur + sroff);

            f2 uA = (f2){U.x, U.y}, uB = (f2){U.z, U.w};
            f2 dA = (f2){D.x, D.y}, dB = (f2){D.z, D.w};

            // Row 0  (up = LDS U, down = old row1)
            f2 LA, M, RB, nA0, nB0, nA1, nB1, nA2, nB2, nA3, nB3;
            LA = (f2){SL.x, vA0.x}; M = (f2){vA0.y, vB0.x}; RB = (f2){vB0.y, SR.x};
            nA0 = pairv(vA0, LA, M, uA, vA1, a2A[0], nk2A[0], m4);
            nB0 = pairv(vB0, M, RB, uB, vB1, a2B[0], nk2B[0], m4);
            // Row 1  (up = old row0, down = old row2)
            LA = (f2){SL.y, vA1.x}; M = (f2){vA1.y, vB1.x}; RB = (f2){vB1.y, SR.y};
            nA1 = pairv(vA1, LA, M, vA0, vA2, a2A[1], nk2A[1], m4);
            nB1 = pairv(vB1, M, RB, vB0, vB2, a2B[1], nk2B[1], m4);
            // Row 2  (up = old row1, down = old row3)
            LA = (f2){SL.z, vA2.x}; M = (f2){vA2.y, vB2.x}; RB = (f2){vB2.y, SR.z};
            nA2 = pairv(vA2, LA, M, vA1, vA3, a2A[2], nk2A[2], m4);
            nB2 = pairv(vB2, M, RB, vB1, vB3, a2B[2], nk2B[2], m4);
            // Row 3  (up = old row2, down = LDS D)
            LA = (f2){SL.w, vA3.x}; M = (f2){vA3.y, vB3.x}; RB = (f2){vB3.y, SR.w};
            nA3 = pairv(vA3, LA, M, vA2, dA, a2A[3], nk2A[3], m4);
            nB3 = pairv(vB3, M, RB, vB2, dB, a2B[3], nk2B[3], m4);

            if (istop) { nA0 = nA1; nB0 = nB1; }     // row replicas first
            if (isbot) { nA3 = nA2; nB3 = nB2; }
            if (isl) { nA0.x = nA0.y; nA1.x = nA1.y; // column replicas
                       nA2.x = nA2.y; nA3.x = nA3.y; }
            if (isr) { nB0.y = nB0.x; nB1.y = nB1.x;
                       nB2.y = nB2.x; nB3.y = nB3.x; }

            // LDS plane writes (pair-granular; compiler may merge to b128)
            *(f2*)(nxt + w0off)     = nA0;  *(f2*)(nxt + w0off + 2) = nB0;
            *(f2*)(nxt + w3off)     = nA3;  *(f2*)(nxt + w3off + 2) = nB3;
            *(f2*)(nxt + wsloff)     = (f2){nB0.y, nB1.y};
            *(f2*)(nxt + wsloff + 2) = (f2){nB2.y, nB3.y};
            *(f2*)(nxt + wsroff)     = (f2){nA0.x, nA1.x};
            *(f2*)(nxt + wsroff + 2) = (f2){nA2.x, nA3.x};

            if (core && t <= tmax) {
                float* slab = out + (long)(base + t - 1) * GNN;
                *(f2*)(slab + gbase)              = nA0;
                *(f2*)(slab + gbase + 2)          = nB0;
                *(f2*)(slab + gbase + GN)         = nA1;
                *(f2*)(slab + gbase + GN + 2)     = nB1;
                *(f2*)(slab + gbase + 2 * GN)     = nA2;
                *(f2*)(slab + gbase + 2 * GN + 2) = nB2;
                *(f2*)(slab + gbase + 3 * GN)     = nA3;
                *(f2*)(slab + gbase + 3 * GN + 2) = nB3;
            }
            vA0 = nA0; vB0 = nB0; vA1 = nA1; vB1 = nB1;
            vA2 = nA2; vB2 = nB2; vA3 = nA3; vB3 = nB3;
        }
        lds_barrier();   // LDS-only wait; global stores drain in background
    }
}

extern "C" void kernel_launch(void* const* d_in, const int* in_sizes, int n_in,
                              void* d_out, int out_size, void* d_ws, size_t ws_size,
                              hipStream_t stream) {
    const float* u0    = (const float*)d_in[0];
    const float* alpha = (const float*)d_in[1];
    const float* kappa = (const float*)d_in[2];
    float* out = (float*)d_out;

    dim3 grd(GN / TI, GN / TI, 1);   // 16x16 = 256 blocks = 1/CU
    dim3 blk(NTHR, 1, 1);

    bool use_ws = ws_size >= (size_t)2 * GNN * sizeof(float);

    if (use_ws) {
        float* a2map = (float*)d_ws;
        float* k2map = a2map + GNN;
        resize_maps_kernel<<<(GNN + 255) / 256, 256, 0, stream>>>(alpha, kappa, a2map, k2map);
        for (int b = 0; b < NOUT; b += KH) {
            const float* src = (b == 0) ? u0 : out + (long)(b - 1) * GNN;
            fused_steps_kernel<true><<<grd, blk, 0, stream>>>(src, a2map, k2map, out, b);
        }
    } else {
        for (int b = 0; b < NOUT; b += KH) {
            const float* src = (b == 0) ? u0 : out + (long)(b - 1) * GNN;
            fused_steps_kernel<false><<<grd, blk, 0, stream>>>(src, alpha, kappa, out, b);
        }
    }
}